// Round 7
// baseline (438.768 us; speedup 1.0000x reference)
//
#include <hip/hip_runtime.h>
#include <math.h>

// 2-layer GAT. bf16 MFMA GEMMs with fused attention-scalar tiles (a_i/a_j come
// out of the GEMM as extra MFMA B-tiles of att-folded weights), fused fp32->bf16
// A-conversion, single-pass segment softmax, quarter-wave (16-lane) gather in
// the aggregations: 4 edges in flight per wave, zero cross-lane ops per edge.

typedef short bfrag __attribute__((ext_vector_type(8)));   // 8 bf16 (4 VGPRs)
typedef float f32x4 __attribute__((ext_vector_type(4)));

__device__ __forceinline__ float lrelu02(float x){ return x > 0.f ? x : 0.2f*x; }
__device__ __forceinline__ unsigned short f2bf(float f){
  unsigned int b = __float_as_uint(f);
  return (unsigned short)((b + 0x7fffu + ((b>>16)&1u)) >> 16);   // RNE
}
__device__ __forceinline__ float bfl(unsigned int u){ return __uint_as_float(u<<16); }
__device__ __forceinline__ float bfh(unsigned int u){ return __uint_as_float(u & 0xffff0000u); }

// ---------------- graph build ----------------
__global__ void k_rank(const int* __restrict__ dst, int* __restrict__ deg,
                       int* __restrict__ rank, int E){
  int i = blockIdx.x*blockDim.x + threadIdx.x;
  if (i < E) rank[i] = atomicAdd(&deg[dst[i]], 1);
}

__global__ void k_scanA(const int* __restrict__ deg, int* __restrict__ rowstart,
                        int* __restrict__ bsum, int N){
  __shared__ int lds[256];
  int t = threadIdx.x;
  int base = blockIdx.x*1024 + t*4;
  int v0 = (base+0<N)?deg[base+0]:0;
  int v1 = (base+1<N)?deg[base+1]:0;
  int v2 = (base+2<N)?deg[base+2]:0;
  int v3 = (base+3<N)?deg[base+3]:0;
  lds[t] = v0+v1+v2+v3;
  __syncthreads();
  for (int off=1; off<256; off<<=1){
    int x = (t>=off)? lds[t-off] : 0;
    __syncthreads();
    lds[t] += x;
    __syncthreads();
  }
  int run = (t==0)? 0 : lds[t-1];
  if (base+0<N) rowstart[base+0]=run;
  run += v0;
  if (base+1<N) rowstart[base+1]=run;
  run += v1;
  if (base+2<N) rowstart[base+2]=run;
  run += v2;
  if (base+3<N) rowstart[base+3]=run;
  if (t==255) bsum[blockIdx.x] = lds[255];
}

__global__ void k_scanB(int* bsum, int nblk){
  __shared__ int lds[128];
  int t = threadIdx.x;
  lds[t] = (t<nblk)? bsum[t] : 0;
  __syncthreads();
  for (int off=1; off<128; off<<=1){
    int x = (t>=off)? lds[t-off] : 0;
    __syncthreads();
    lds[t] += x;
    __syncthreads();
  }
  if (t<nblk) bsum[t] = (t==0)? 0 : lds[t-1];
}

__global__ void k_scanC(int* rowstart, const int* __restrict__ bsum, int N, int E){
  int i = blockIdx.x*blockDim.x + threadIdx.x;
  if (i < N) rowstart[i] += bsum[i>>10];
  if (i == 0) rowstart[N] = E;
}

// XCD-partitioned scatter: block b&7 owns a node range -> each csr line written
// from one XCD only (no cross-XCD partial-line write-allocate thrash).
__global__ void k_fillx(const int* __restrict__ src, const int* __restrict__ dst,
                        const int* __restrict__ rank, const int* __restrict__ rowstart,
                        int* __restrict__ csr, int E, int N){
  int xcd = blockIdx.x & 7;
  int blk = blockIdx.x >> 3;
  int nchunk = gridDim.x >> 3;
  int r0 = xcd*(N/8), r1 = (xcd==7)? N : (xcd+1)*(N/8);
  int per = (E + nchunk - 1)/nchunk;
  int lo = blk*per, hi = min(lo+per, E);
  for (int i = lo + threadIdx.x; i < hi; i += blockDim.x){
    int d = dst[i];
    if (d >= r0 && d < r1) csr[rowstart[d] + rank[i]] = src[i];
  }
}

// ---------------- weight prep: bf16 weights + att-folded tiles + bias consts ----------------
// attB1 row j (j<8: i-half head j; j>=8: j-half head j-8): V[j][k] = sum_c att1[h,c?]*W1[h*16+c][k]
// attB2 row 0 = att2_i @ W2, row 1 = att2_j @ W2, rows 2..15 zero.
// consts[0..7]=sum_c b1[h*16+c]att1[h,c]; [8..15] j-half; [16],[17] layer2.
__global__ void k_prep(const float* __restrict__ W1, const float* __restrict__ b1,
                       const float* __restrict__ att1,
                       const float* __restrict__ W2, const float* __restrict__ b2,
                       const float* __restrict__ att2,
                       unsigned short* __restrict__ W1b, unsigned short* __restrict__ W2b,
                       unsigned short* __restrict__ attB1, unsigned short* __restrict__ attB2,
                       float* __restrict__ consts){
  int i = blockIdx.x*blockDim.x + threadIdx.x;
  if (i < 16384){ W1b[i] = f2bf(W1[i]); return; }
  i -= 16384;
  if (i < 6144){ int r = i >> 7; W2b[i] = (r < 40)? f2bf(W2[i]) : (unsigned short)0; return; }
  i -= 6144;
  if (i < 2048){
    int j = i >> 7, k = i & 127;
    int h = j & 7, half = (j >> 3)*16;
    float s = 0.f;
    for (int c = 0; c < 16; ++c) s += att1[h*32 + half + c]*W1[(h*16+c)*128 + k];
    attB1[i] = f2bf(s); return;
  }
  i -= 2048;
  if (i < 2048){
    int j = i >> 7, k = i & 127;
    float s = 0.f;
    if (j < 2){ const float* av = att2 + j*40; for (int c = 0; c < 40; ++c) s += av[c]*W2[c*128 + k]; }
    attB2[i] = f2bf(s); return;
  }
  i -= 2048;
  if (i < 18){
    float s = 0.f;
    if (i < 8){ for (int c = 0; c < 16; ++c) s += b1[i*16+c]*att1[i*32+c]; }
    else if (i < 16){ int h = i-8; for (int c = 0; c < 16; ++c) s += b1[h*16+c]*att1[h*32+16+c]; }
    else if (i == 16){ for (int c = 0; c < 40; ++c) s += b2[c]*att2[c]; }
    else { for (int c = 0; c < 40; ++c) s += b2[c]*att2[40+c]; }
    consts[i] = s;
  }
}

// ---------------- GEMM1 (MFMA): h1b + a1i/a1j from fp32 x directly ----------------
// 9 B-tiles: 0..7 = W1 (128 oc), 8 = attB1 (a1i cols 0..7, a1j cols 8..15).
__global__ __launch_bounds__(256) void k_gemm1(const float* __restrict__ x,
    const unsigned short* __restrict__ Wb, const unsigned short* __restrict__ attB,
    const float* __restrict__ b1, const float* __restrict__ consts,
    unsigned short* __restrict__ h1b, float* __restrict__ a1i, float* __restrict__ a1j, int N){
  int wid  = (blockIdx.x*256 + threadIdx.x) >> 6;
  int lane = threadIdx.x & 63;
  int m0 = wid*16;
  if (m0 >= N) return;
  int col = lane & 15, quad = lane >> 4;
  const float* xr = x + (size_t)(m0+col)*128 + quad*8;
  f32x4 acc[9];
  #pragma unroll
  for (int t=0;t<9;t++){ acc[t][0]=0.f; acc[t][1]=0.f; acc[t][2]=0.f; acc[t][3]=0.f; }
  #pragma unroll
  for (int q=0;q<4;q++){
    float4 f0 = ((const float4*)(xr + q*32))[0];
    float4 f1 = ((const float4*)(xr + q*32))[1];
    bfrag a;
    a[0]=(short)f2bf(f0.x); a[1]=(short)f2bf(f0.y); a[2]=(short)f2bf(f0.z); a[3]=(short)f2bf(f0.w);
    a[4]=(short)f2bf(f1.x); a[5]=(short)f2bf(f1.y); a[6]=(short)f2bf(f1.z); a[7]=(short)f2bf(f1.w);
    #pragma unroll
    for (int t=0;t<8;t++){
      const bfrag* Bp = (const bfrag*)(Wb + (size_t)(t*16+col)*128 + q*32 + quad*8);
      acc[t] = __builtin_amdgcn_mfma_f32_16x16x32_bf16(a, *Bp, acc[t], 0,0,0);
    }
    const bfrag* Ap = (const bfrag*)(attB + (size_t)col*128 + q*32 + quad*8);
    acc[8] = __builtin_amdgcn_mfma_f32_16x16x32_bf16(a, *Ap, acc[8], 0,0,0);
  }
  #pragma unroll
  for (int t=0;t<8;t++){
    int c = t*16 + col;
    float bb = b1[c];
    #pragma unroll
    for (int r=0;r<4;r++){
      h1b[(size_t)(m0 + quad*4 + r)*128 + c] = f2bf(acc[t][r] + bb);
    }
  }
  float hb = consts[col];
  #pragma unroll
  for (int r=0;r<4;r++){
    int node = m0 + quad*4 + r;
    float v = acc[8][r] + hb;
    if (col < 8) a1i[node*8 + col] = v;
    else         a1j[node*8 + (col-8)] = v;
  }
}

// ---------------- layer-1 fused softmax+aggregate: quarter-wave gather ----------------
// one wave per node; quarter qt (16 lanes) handles edge e0+qt; lane ql owns
// channels 8*ql..8*ql+7 (uint4), head = ql>>1. No cross-lane ops in the loop.
__global__ __launch_bounds__(256) void k_agg1(const uint4* __restrict__ h1u4,
    const float* __restrict__ a1i, const float* __restrict__ a1j,
    const int* __restrict__ rowstart, const int* __restrict__ csr,
    const float* __restrict__ bias, uint4* __restrict__ x2u4, int N){
  int lane = threadIdx.x & 63;
  int n = (blockIdx.x*blockDim.x + threadIdx.x) >> 6;
  if (n >= N) return;
  int ql = lane & 15, qt = lane >> 4;
  unsigned hd = (unsigned)ql >> 1;
  int rs = rowstart[n], re = rowstart[n+1];
  float ai2 = a1i[(unsigned)n*8u + hd];
  float acc0=0.f,acc1=0.f,acc2=0.f,acc3=0.f,acc4=0.f,acc5=0.f,acc6=0.f,acc7=0.f,den=0.f;
  {
    float wself = __expf(lrelu02(ai2 + a1j[(unsigned)n*8u + hd]));
    uint4 u = h1u4[(unsigned)n*16u + (unsigned)ql];
    if (qt == 0){
      den = wself;
      acc0=wself*bfl(u.x); acc1=wself*bfh(u.x); acc2=wself*bfl(u.y); acc3=wself*bfh(u.y);
      acc4=wself*bfl(u.z); acc5=wself*bfh(u.z); acc6=wself*bfl(u.w); acc7=wself*bfh(u.w);
    }
  }
  int last = re - 1;
  unsigned csA=0u, csB=0u; float ajA=0.f, ajB=0.f;
  if (rs < re){ csA = (unsigned)csr[min(rs+qt, last)];   ajA = a1j[csA*8u + hd]; }
  if (rs+4 < re){ csB = (unsigned)csr[min(rs+4+qt, last)]; ajB = a1j[csB*8u + hd]; }
  int e0 = rs;
  while (e0 < re){
    { // slot A: edges e0..e0+3
      float w = (e0+qt < re)? __expf(lrelu02(ai2 + ajA)) : 0.f;
      uint4 u = h1u4[csA*16u + (unsigned)ql];
      if (e0+8 < re){ unsigned nc=(unsigned)csr[min(e0+8+qt,last)]; csA=nc; ajA=a1j[nc*8u+hd]; }
      den += w;
      acc0 += w*bfl(u.x); acc1 += w*bfh(u.x); acc2 += w*bfl(u.y); acc3 += w*bfh(u.y);
      acc4 += w*bfl(u.z); acc5 += w*bfh(u.z); acc6 += w*bfl(u.w); acc7 += w*bfh(u.w);
    }
    e0 += 4;
    if (e0 >= re) break;
    { // slot B
      float w = (e0+qt < re)? __expf(lrelu02(ai2 + ajB)) : 0.f;
      uint4 u = h1u4[csB*16u + (unsigned)ql];
      if (e0+8 < re){ unsigned nc=(unsigned)csr[min(e0+8+qt,last)]; csB=nc; ajB=a1j[nc*8u+hd]; }
      den += w;
      acc0 += w*bfl(u.x); acc1 += w*bfh(u.x); acc2 += w*bfl(u.y); acc3 += w*bfh(u.y);
      acc4 += w*bfl(u.z); acc5 += w*bfh(u.z); acc6 += w*bfl(u.w); acc7 += w*bfh(u.w);
    }
    e0 += 4;
  }
  // combine quarters (lanes l, l^16, l^32, l^48 share ql)
  den  += __shfl_xor(den, 16);  den  += __shfl_xor(den, 32);
  acc0 += __shfl_xor(acc0,16); acc0 += __shfl_xor(acc0,32);
  acc1 += __shfl_xor(acc1,16); acc1 += __shfl_xor(acc1,32);
  acc2 += __shfl_xor(acc2,16); acc2 += __shfl_xor(acc2,32);
  acc3 += __shfl_xor(acc3,16); acc3 += __shfl_xor(acc3,32);
  acc4 += __shfl_xor(acc4,16); acc4 += __shfl_xor(acc4,32);
  acc5 += __shfl_xor(acc5,16); acc5 += __shfl_xor(acc5,32);
  acc6 += __shfl_xor(acc6,16); acc6 += __shfl_xor(acc6,32);
  acc7 += __shfl_xor(acc7,16); acc7 += __shfl_xor(acc7,32);
  float invd = 1.f/(den + 1e-16f);
  const float4* b4 = (const float4*)(bias + 8*ql);
  float4 bl = b4[0], bh = b4[1];
  float o0=acc0*invd+bl.x, o1=acc1*invd+bl.y, o2=acc2*invd+bl.z, o3=acc3*invd+bl.w;
  float o4=acc4*invd+bh.x, o5=acc5*invd+bh.y, o6=acc6*invd+bh.z, o7=acc7*invd+bh.w;
  o0=(o0>0.f)?o0:(__expf(o0)-1.f); o1=(o1>0.f)?o1:(__expf(o1)-1.f);
  o2=(o2>0.f)?o2:(__expf(o2)-1.f); o3=(o3>0.f)?o3:(__expf(o3)-1.f);
  o4=(o4>0.f)?o4:(__expf(o4)-1.f); o5=(o5>0.f)?o5:(__expf(o5)-1.f);
  o6=(o6>0.f)?o6:(__expf(o6)-1.f); o7=(o7>0.f)?o7:(__expf(o7)-1.f);
  if (qt == 0){
    uint4 o;
    o.x = ((unsigned)f2bf(o1)<<16) | f2bf(o0);
    o.y = ((unsigned)f2bf(o3)<<16) | f2bf(o2);
    o.z = ((unsigned)f2bf(o5)<<16) | f2bf(o4);
    o.w = ((unsigned)f2bf(o7)<<16) | f2bf(o6);
    x2u4[(unsigned)n*16u + (unsigned)ql] = o;
  }
}

// ---------------- GEMM2 (MFMA): h2b + a2i/a2j ----------------
// 4 B-tiles: 0..2 = W2 (40 oc + pad), 3 = attB2 (col0 -> a2i, col1 -> a2j).
__global__ __launch_bounds__(256) void k_gemm2(const unsigned short* __restrict__ xb,
    const unsigned short* __restrict__ Wb, const unsigned short* __restrict__ attB,
    const float* __restrict__ b2, const float* __restrict__ consts,
    unsigned short* __restrict__ h2b, float* __restrict__ a2i, float* __restrict__ a2j, int N){
  int wid  = (blockIdx.x*256 + threadIdx.x) >> 6;
  int lane = threadIdx.x & 63;
  int m0 = wid*16;
  if (m0 >= N) return;
  int col = lane & 15, quad = lane >> 4;
  const bfrag* A8 = (const bfrag*)(xb + (size_t)(m0+col)*128 + quad*8);
  f32x4 acc[4];
  #pragma unroll
  for (int t=0;t<4;t++){ acc[t][0]=0.f; acc[t][1]=0.f; acc[t][2]=0.f; acc[t][3]=0.f; }
  #pragma unroll
  for (int q=0;q<4;q++){
    bfrag a = A8[q*4];
    #pragma unroll
    for (int t=0;t<3;t++){
      const bfrag* Bp = (const bfrag*)(Wb + (size_t)(t*16+col)*128 + q*32 + quad*8);
      acc[t] = __builtin_amdgcn_mfma_f32_16x16x32_bf16(a, *Bp, acc[t], 0,0,0);
    }
    const bfrag* Ap = (const bfrag*)(attB + (size_t)col*128 + q*32 + quad*8);
    acc[3] = __builtin_amdgcn_mfma_f32_16x16x32_bf16(a, *Ap, acc[3], 0,0,0);
  }
  #pragma unroll
  for (int t=0;t<3;t++){
    int c = t*16 + col;
    if (c < 40){
      float bb = b2[c];
      #pragma unroll
      for (int r=0;r<4;r++){
        h2b[(size_t)(m0 + quad*4 + r)*40 + c] = f2bf(acc[t][r] + bb);
      }
    }
  }
  if (col < 2){
    float cc = consts[16 + col];
    #pragma unroll
    for (int r=0;r<4;r++){
      int node = m0 + quad*4 + r;
      if (col == 0) a2i[node] = acc[3][r] + cc;
      else          a2j[node] = acc[3][r] + cc;
    }
  }
}

// ---------------- layer-2 fused softmax+aggregate + log_softmax ----------------
// FOUR nodes per wave: quarter qt owns node wid*4+qt; lanes ql<10 hold channel
// quads (uint2). Per-quarter independent edge loop (no cross-quarter reduction).
__global__ __launch_bounds__(256) void k_agg2(const uint2* __restrict__ h2u2,
    const float* __restrict__ a2i, const float* __restrict__ a2j,
    const int* __restrict__ rowstart, const int* __restrict__ csr,
    const float* __restrict__ bias, float* __restrict__ out, int N){
  int lane = threadIdx.x & 63;
  int wid = (blockIdx.x*blockDim.x + threadIdx.x) >> 6;
  int qt = lane >> 4, ql = lane & 15;
  int n = wid*4 + qt;
  if (n >= N) return;
  bool act = ql < 10;
  unsigned cl = act ? (unsigned)ql : 0u;
  int rs = rowstart[n], re = rowstart[n+1];
  float ai = a2i[n];
  float wself = __expf(lrelu02(ai + a2j[n]));
  uint2 us = h2u2[(unsigned)n*10u + cl];
  float acc0=wself*bfl(us.x), acc1=wself*bfh(us.x), acc2=wself*bfl(us.y), acc3=wself*bfh(us.y);
  float den = wself;
  unsigned csA=0u, csB=0u; float ajA=0.f, ajB=0.f;
  if (rs < re){ csA = (unsigned)csr[rs]; ajA = a2j[csA]; }
  if (rs+1 < re){ csB = (unsigned)csr[rs+1]; ajB = a2j[csB]; }
  for (int e = rs; e < re; ++e){
    float w = __expf(lrelu02(ai + ajA));
    uint2 u = h2u2[csA*10u + cl];
    csA = csB; ajA = ajB;
    if (e+2 < re){ csB = (unsigned)csr[e+2]; ajB = a2j[csB]; }
    den += w;
    acc0 += w*bfl(u.x); acc1 += w*bfh(u.x); acc2 += w*bfl(u.y); acc3 += w*bfh(u.y);
  }
  float invd = 1.f/(den + 1e-16f);
  const float4* b4 = (const float4*)(bias + 4*cl);
  float4 bb = b4[0];
  float v0 = acc0*invd + bb.x, v1 = acc1*invd + bb.y;
  float v2 = acc2*invd + bb.z, v3 = acc3*invd + bb.w;
  float mv = act ? fmaxf(fmaxf(v0,v1), fmaxf(v2,v3)) : -INFINITY;
  #pragma unroll
  for (int off = 1; off < 16; off <<= 1) mv = fmaxf(mv, __shfl_xor(mv, off));
  float se = act ? (__expf(v0-mv)+__expf(v1-mv)+__expf(v2-mv)+__expf(v3-mv)) : 0.f;
  #pragma unroll
  for (int off = 1; off < 16; off <<= 1) se += __shfl_xor(se, off);
  float ls = __logf(se);
  if (act){
    float4 o = make_float4(v0-mv-ls, v1-mv-ls, v2-mv-ls, v3-mv-ls);
    ((float4*)out)[(unsigned)n*10u + cl] = o;
  }
}

extern "C" void kernel_launch(void* const* d_in, const int* in_sizes, int n_in,
                              void* d_out, int out_size, void* d_ws, size_t ws_size,
                              hipStream_t stream){
  const float* x     = (const float*)d_in[0];
  const int*   ei    = (const int*)  d_in[1];
  const float* W1    = (const float*)d_in[2];
  const float* b1    = (const float*)d_in[3];
  const float* att1  = (const float*)d_in[4];
  const float* bias1 = (const float*)d_in[5];
  const float* W2    = (const float*)d_in[6];
  const float* b2    = (const float*)d_in[7];
  const float* att2  = (const float*)d_in[8];
  const float* bias2 = (const float*)d_in[9];
  int N = in_sizes[0] / 128;
  int E = in_sizes[1] / 2;
  const int* src = ei;
  const int* dst = ei + E;

  char* ws = (char*)d_ws;
  size_t off = 0;
  auto alloc = [&](size_t bytes)->char*{
    char* p = ws + off; off += (bytes + 255) & ~(size_t)255; return p;
  };
  unsigned short* h1b = (unsigned short*)alloc((size_t)N*128*2);
  unsigned short* x2b = (unsigned short*)alloc((size_t)N*128*2);
  unsigned short* h2b = (unsigned short*)alloc((size_t)N*40*2);
  float* a1i  = (float*)alloc((size_t)N*8*4);
  float* a1j  = (float*)alloc((size_t)N*8*4);
  float* a2i  = (float*)alloc((size_t)N*4);
  float* a2j  = (float*)alloc((size_t)N*4);
  unsigned short* W1b   = (unsigned short*)alloc(16384*2);
  unsigned short* W2b   = (unsigned short*)alloc(6144*2);
  unsigned short* attB1 = (unsigned short*)alloc(2048*2);
  unsigned short* attB2 = (unsigned short*)alloc(2048*2);
  float* consts = (float*)alloc(18*4);
  int*   deg  = (int*)  alloc((size_t)N*4);
  int*   rank = (int*)  alloc((size_t)E*4);
  int*   rowst= (int*)  alloc((size_t)(N+1)*4);
  int*   csr  = (int*)  alloc((size_t)E*4);
  int*   bsum = (int*)  alloc(4096);

  hipMemsetAsync(deg, 0, (size_t)N*4, stream);
  int nblk = (N + 1023)/1024;
  k_rank<<<(E+255)/256, 256, 0, stream>>>(dst, deg, rank, E);
  k_scanA<<<nblk, 256, 0, stream>>>(deg, rowst, bsum, N);
  k_scanB<<<1, 128, 0, stream>>>(bsum, nblk);
  k_scanC<<<(N+255)/256, 256, 0, stream>>>(rowst, bsum, N, E);
  k_fillx<<<1024, 256, 0, stream>>>(src, dst, rank, rowst, csr, E, N);
  k_prep<<<105, 256, 0, stream>>>(W1, b1, att1, W2, b2, att2, W1b, W2b, attB1, attB2, consts);

  int gblk = ((N+15)/16 + 3)/4;  // 4 waves/block, 16 nodes/wave
  k_gemm1<<<gblk, 256, 0, stream>>>(x, W1b, attB1, b1, consts, h1b, a1i, a1j, N);
  k_agg1<<<(N*64+255)/256, 256, 0, stream>>>((const uint4*)h1b, a1i, a1j, rowst, csr, bias1, (uint4*)x2b, N);

  k_gemm2<<<gblk, 256, 0, stream>>>(x2b, W2b, attB2, b2, consts, h2b, a2i, a2j, N);
  k_agg2<<<(N+15)/16, 256, 0, stream>>>((const uint2*)h2b, a2i, a2j, rowst, csr, bias2, (float*)d_out, N);
}

// Round 8
// 435.329 us; speedup vs baseline: 1.0079x; 1.0079x over previous
//
#include <hip/hip_runtime.h>
#include <hip/hip_fp16.h>
#include <math.h>

// 2-layer GAT, f16 pipeline: f16 MFMA GEMMs with fused attention-scalar tiles,
// single-pass segment softmax, quarter-wave gather aggregation with packed
// v_pk_fma_f16 accumulation (no unpack VALU), XCD-partitioned CSR build.

typedef _Float16 f16x8 __attribute__((ext_vector_type(8)));   // 8 f16 (4 VGPRs)
typedef float f32x4 __attribute__((ext_vector_type(4)));

__device__ __forceinline__ float lrelu02(float x){ return x > 0.f ? x : 0.2f*x; }

// ---------------- graph build ----------------
__global__ void k_rank(const int* __restrict__ dst, int* __restrict__ deg,
                       int* __restrict__ rank, int E){
  int i = blockIdx.x*blockDim.x + threadIdx.x;
  if (i < E) rank[i] = atomicAdd(&deg[dst[i]], 1);
}

__global__ void k_scanA(const int* __restrict__ deg, int* __restrict__ rowstart,
                        int* __restrict__ bsum, int N){
  __shared__ int lds[256];
  int t = threadIdx.x;
  int base = blockIdx.x*1024 + t*4;
  int v0 = (base+0<N)?deg[base+0]:0;
  int v1 = (base+1<N)?deg[base+1]:0;
  int v2 = (base+2<N)?deg[base+2]:0;
  int v3 = (base+3<N)?deg[base+3]:0;
  lds[t] = v0+v1+v2+v3;
  __syncthreads();
  for (int off=1; off<256; off<<=1){
    int x = (t>=off)? lds[t-off] : 0;
    __syncthreads();
    lds[t] += x;
    __syncthreads();
  }
  int run = (t==0)? 0 : lds[t-1];
  if (base+0<N) rowstart[base+0]=run;
  run += v0;
  if (base+1<N) rowstart[base+1]=run;
  run += v1;
  if (base+2<N) rowstart[base+2]=run;
  run += v2;
  if (base+3<N) rowstart[base+3]=run;
  if (t==255) bsum[blockIdx.x] = lds[255];
}

__global__ void k_scanB(int* bsum, int nblk){
  __shared__ int lds[128];
  int t = threadIdx.x;
  lds[t] = (t<nblk)? bsum[t] : 0;
  __syncthreads();
  for (int off=1; off<128; off<<=1){
    int x = (t>=off)? lds[t-off] : 0;
    __syncthreads();
    lds[t] += x;
    __syncthreads();
  }
  if (t<nblk) bsum[t] = (t==0)? 0 : lds[t-1];
}

__global__ void k_scanC(int* rowstart, const int* __restrict__ bsum, int N, int E){
  int i = blockIdx.x*blockDim.x + threadIdx.x;
  if (i < N) rowstart[i] += bsum[i>>10];
  if (i == 0) rowstart[N] = E;
}

// XCD-partitioned scatter: block b&7 owns a node range -> each csr line written
// from one XCD only (no cross-XCD partial-line write-allocate thrash).
__global__ void k_fillx(const int* __restrict__ src, const int* __restrict__ dst,
                        const int* __restrict__ rank, const int* __restrict__ rowstart,
                        int* __restrict__ csr, int E, int N){
  int xcd = blockIdx.x & 7;
  int blk = blockIdx.x >> 3;
  int nchunk = gridDim.x >> 3;
  int r0 = xcd*(N/8), r1 = (xcd==7)? N : (xcd+1)*(N/8);
  int per = (E + nchunk - 1)/nchunk;
  int lo = blk*per, hi = min(lo+per, E);
  for (int i = lo + threadIdx.x; i < hi; i += blockDim.x){
    int d = dst[i];
    if (d >= r0 && d < r1) csr[rowstart[d] + rank[i]] = src[i];
  }
}

// ---------------- weight prep: f16 weights + att-folded tiles + bias consts ----------------
__global__ void k_prep(const float* __restrict__ W1, const float* __restrict__ b1,
                       const float* __restrict__ att1,
                       const float* __restrict__ W2, const float* __restrict__ b2,
                       const float* __restrict__ att2,
                       _Float16* __restrict__ W1h, _Float16* __restrict__ W2h,
                       _Float16* __restrict__ attB1, _Float16* __restrict__ attB2,
                       float* __restrict__ consts){
  int i = blockIdx.x*blockDim.x + threadIdx.x;
  if (i < 16384){ W1h[i] = (_Float16)W1[i]; return; }
  i -= 16384;
  if (i < 6144){ int r = i >> 7; W2h[i] = (r < 40)? (_Float16)W2[i] : (_Float16)0.f; return; }
  i -= 6144;
  if (i < 2048){
    int j = i >> 7, k = i & 127;
    int h = j & 7, half = (j >> 3)*16;
    float s = 0.f;
    for (int c = 0; c < 16; ++c) s += att1[h*32 + half + c]*W1[(h*16+c)*128 + k];
    attB1[i] = (_Float16)s; return;
  }
  i -= 2048;
  if (i < 2048){
    int j = i >> 7, k = i & 127;
    float s = 0.f;
    if (j < 2){ const float* av = att2 + j*40; for (int c = 0; c < 40; ++c) s += av[c]*W2[c*128 + k]; }
    attB2[i] = (_Float16)s; return;
  }
  i -= 2048;
  if (i < 18){
    float s = 0.f;
    if (i < 8){ for (int c = 0; c < 16; ++c) s += b1[i*16+c]*att1[i*32+c]; }
    else if (i < 16){ int h = i-8; for (int c = 0; c < 16; ++c) s += b1[h*16+c]*att1[h*32+16+c]; }
    else if (i == 16){ for (int c = 0; c < 40; ++c) s += b2[c]*att2[c]; }
    else { for (int c = 0; c < 40; ++c) s += b2[c]*att2[40+c]; }
    consts[i] = s;
  }
}

// ---------------- GEMM1 (MFMA f16): h1h[N,128] + a1i/a1j from fp32 x ----------------
// 9 B-tiles: 0..7 = W1 (128 oc), 8 = attB1 (a1i cols 0..7, a1j cols 8..15).
__global__ __launch_bounds__(256) void k_gemm1(const float* __restrict__ x,
    const _Float16* __restrict__ Wh, const _Float16* __restrict__ attB,
    const float* __restrict__ b1, const float* __restrict__ consts,
    _Float16* __restrict__ h1h, float* __restrict__ a1i, float* __restrict__ a1j, int N){
  int wid  = (blockIdx.x*256 + threadIdx.x) >> 6;
  int lane = threadIdx.x & 63;
  int m0 = wid*16;
  if (m0 >= N) return;
  int col = lane & 15, quad = lane >> 4;
  const float* xr = x + (size_t)(m0+col)*128 + quad*8;
  f32x4 acc[9];
  #pragma unroll
  for (int t=0;t<9;t++){ acc[t][0]=0.f; acc[t][1]=0.f; acc[t][2]=0.f; acc[t][3]=0.f; }
  #pragma unroll
  for (int q=0;q<4;q++){
    float4 f0 = ((const float4*)(xr + q*32))[0];
    float4 f1 = ((const float4*)(xr + q*32))[1];
    f16x8 a;
    a[0]=(_Float16)f0.x; a[1]=(_Float16)f0.y; a[2]=(_Float16)f0.z; a[3]=(_Float16)f0.w;
    a[4]=(_Float16)f1.x; a[5]=(_Float16)f1.y; a[6]=(_Float16)f1.z; a[7]=(_Float16)f1.w;
    #pragma unroll
    for (int t=0;t<8;t++){
      const f16x8* Bp = (const f16x8*)(Wh + (size_t)(t*16+col)*128 + q*32 + quad*8);
      acc[t] = __builtin_amdgcn_mfma_f32_16x16x32_f16(a, *Bp, acc[t], 0,0,0);
    }
    const f16x8* Ap = (const f16x8*)(attB + (size_t)col*128 + q*32 + quad*8);
    acc[8] = __builtin_amdgcn_mfma_f32_16x16x32_f16(a, *Ap, acc[8], 0,0,0);
  }
  #pragma unroll
  for (int t=0;t<8;t++){
    int c = t*16 + col;
    float bb = b1[c];
    #pragma unroll
    for (int r=0;r<4;r++){
      h1h[(size_t)(m0 + quad*4 + r)*128 + c] = (_Float16)(acc[t][r] + bb);
    }
  }
  float hb = consts[col];
  #pragma unroll
  for (int r=0;r<4;r++){
    int node = m0 + quad*4 + r;
    float v = acc[8][r] + hb;
    if (col < 8) a1i[node*8 + col] = v;
    else         a1j[node*8 + (col-8)] = v;
  }
}

// ---------------- layer-1 fused softmax+aggregate: quarter-wave, pk_fma_f16 ----------------
// one wave per node; quarter qt handles edge e0+qt; lane ql owns channels
// 8*ql..8*ql+7 (uint4 of f16), head = ql>>1. No unpack: __hfma2 on packed pairs.
__global__ __launch_bounds__(256) void k_agg1(const uint4* __restrict__ h1u4,
    const float* __restrict__ a1i, const float* __restrict__ a1j,
    const int* __restrict__ rowstart, const int* __restrict__ csr,
    const float* __restrict__ bias, uint4* __restrict__ x2u4, int N){
  int lane = threadIdx.x & 63;
  int n = (blockIdx.x*blockDim.x + threadIdx.x) >> 6;
  if (n >= N) return;
  int ql = lane & 15, qt = lane >> 4;
  unsigned hd = (unsigned)ql >> 1;
  int rs = rowstart[n], re = rowstart[n+1];
  float ai2 = a1i[(unsigned)n*8u + hd];
  __half2 acc0, acc1, acc2, acc3;
  float den;
  {
    float wself = (qt==0)? __expf(lrelu02(ai2 + a1j[(unsigned)n*8u + hd])) : 0.f;
    uint4 u = h1u4[(unsigned)n*16u + (unsigned)ql];
    __half2 wh = __float2half2_rn(wself);
    acc0 = __hmul2(wh, *(const __half2*)&u.x);
    acc1 = __hmul2(wh, *(const __half2*)&u.y);
    acc2 = __hmul2(wh, *(const __half2*)&u.z);
    acc3 = __hmul2(wh, *(const __half2*)&u.w);
    den = wself;
  }
  int last = re - 1;
  unsigned csA=0u, csB=0u; float ajA=0.f, ajB=0.f;
  if (rs < re){ csA = (unsigned)csr[min(rs+qt, last)];   ajA = a1j[csA*8u + hd]; }
  if (rs+4 < re){ csB = (unsigned)csr[min(rs+4+qt, last)]; ajB = a1j[csB*8u + hd]; }
  int e0 = rs;
  while (e0 < re){
    { // slot A: edges e0..e0+3
      float w = (e0+qt < re)? __expf(lrelu02(ai2 + ajA)) : 0.f;
      uint4 u = h1u4[csA*16u + (unsigned)ql];
      if (e0+8 < re){ unsigned nc=(unsigned)csr[min(e0+8+qt,last)]; csA=nc; ajA=a1j[nc*8u+hd]; }
      den += w;
      __half2 wh = __float2half2_rn(w);
      acc0 = __hfma2(wh, *(const __half2*)&u.x, acc0);
      acc1 = __hfma2(wh, *(const __half2*)&u.y, acc1);
      acc2 = __hfma2(wh, *(const __half2*)&u.z, acc2);
      acc3 = __hfma2(wh, *(const __half2*)&u.w, acc3);
    }
    e0 += 4;
    if (e0 >= re) break;
    { // slot B
      float w = (e0+qt < re)? __expf(lrelu02(ai2 + ajB)) : 0.f;
      uint4 u = h1u4[csB*16u + (unsigned)ql];
      if (e0+8 < re){ unsigned nc=(unsigned)csr[min(e0+8+qt,last)]; csB=nc; ajB=a1j[nc*8u+hd]; }
      den += w;
      __half2 wh = __float2half2_rn(w);
      acc0 = __hfma2(wh, *(const __half2*)&u.x, acc0);
      acc1 = __hfma2(wh, *(const __half2*)&u.y, acc1);
      acc2 = __hfma2(wh, *(const __half2*)&u.z, acc2);
      acc3 = __hfma2(wh, *(const __half2*)&u.w, acc3);
    }
    e0 += 4;
  }
  float2 f0 = __half22float2(acc0), f1 = __half22float2(acc1);
  float2 f2 = __half22float2(acc2), f3 = __half22float2(acc3);
  float A0=f0.x,A1=f0.y,A2=f1.x,A3=f1.y,A4=f2.x,A5=f2.y,A6=f3.x,A7=f3.y;
  den += __shfl_xor(den, 16); den += __shfl_xor(den, 32);
  A0 += __shfl_xor(A0,16); A0 += __shfl_xor(A0,32);
  A1 += __shfl_xor(A1,16); A1 += __shfl_xor(A1,32);
  A2 += __shfl_xor(A2,16); A2 += __shfl_xor(A2,32);
  A3 += __shfl_xor(A3,16); A3 += __shfl_xor(A3,32);
  A4 += __shfl_xor(A4,16); A4 += __shfl_xor(A4,32);
  A5 += __shfl_xor(A5,16); A5 += __shfl_xor(A5,32);
  A6 += __shfl_xor(A6,16); A6 += __shfl_xor(A6,32);
  A7 += __shfl_xor(A7,16); A7 += __shfl_xor(A7,32);
  if (qt == 0){
    float invd = 1.f/(den + 1e-16f);
    const float4* b4 = (const float4*)(bias + 8*ql);
    float4 bl = b4[0], bh = b4[1];
    float o0=A0*invd+bl.x, o1=A1*invd+bl.y, o2=A2*invd+bl.z, o3=A3*invd+bl.w;
    float o4=A4*invd+bh.x, o5=A5*invd+bh.y, o6=A6*invd+bh.z, o7=A7*invd+bh.w;
    o0=(o0>0.f)?o0:(__expf(o0)-1.f); o1=(o1>0.f)?o1:(__expf(o1)-1.f);
    o2=(o2>0.f)?o2:(__expf(o2)-1.f); o3=(o3>0.f)?o3:(__expf(o3)-1.f);
    o4=(o4>0.f)?o4:(__expf(o4)-1.f); o5=(o5>0.f)?o5:(__expf(o5)-1.f);
    o6=(o6>0.f)?o6:(__expf(o6)-1.f); o7=(o7>0.f)?o7:(__expf(o7)-1.f);
    __half2 p0 = __floats2half2_rn(o0,o1), p1 = __floats2half2_rn(o2,o3);
    __half2 p2 = __floats2half2_rn(o4,o5), p3 = __floats2half2_rn(o6,o7);
    uint4 o;
    o.x = *(unsigned*)&p0; o.y = *(unsigned*)&p1; o.z = *(unsigned*)&p2; o.w = *(unsigned*)&p3;
    x2u4[(unsigned)n*16u + (unsigned)ql] = o;
  }
}

// ---------------- GEMM2 (MFMA f16): h2h + a2i/a2j ----------------
__global__ __launch_bounds__(256) void k_gemm2(const _Float16* __restrict__ xh,
    const _Float16* __restrict__ Wh, const _Float16* __restrict__ attB,
    const float* __restrict__ b2, const float* __restrict__ consts,
    _Float16* __restrict__ h2h, float* __restrict__ a2i, float* __restrict__ a2j, int N){
  int wid  = (blockIdx.x*256 + threadIdx.x) >> 6;
  int lane = threadIdx.x & 63;
  int m0 = wid*16;
  if (m0 >= N) return;
  int col = lane & 15, quad = lane >> 4;
  const f16x8* A8 = (const f16x8*)(xh + (size_t)(m0+col)*128 + quad*8);
  f32x4 acc[4];
  #pragma unroll
  for (int t=0;t<4;t++){ acc[t][0]=0.f; acc[t][1]=0.f; acc[t][2]=0.f; acc[t][3]=0.f; }
  #pragma unroll
  for (int q=0;q<4;q++){
    f16x8 a = A8[q*4];
    #pragma unroll
    for (int t=0;t<3;t++){
      const f16x8* Bp = (const f16x8*)(Wh + (size_t)(t*16+col)*128 + q*32 + quad*8);
      acc[t] = __builtin_amdgcn_mfma_f32_16x16x32_f16(a, *Bp, acc[t], 0,0,0);
    }
    const f16x8* Ap = (const f16x8*)(attB + (size_t)col*128 + q*32 + quad*8);
    acc[3] = __builtin_amdgcn_mfma_f32_16x16x32_f16(a, *Ap, acc[3], 0,0,0);
  }
  #pragma unroll
  for (int t=0;t<3;t++){
    int c = t*16 + col;
    if (c < 40){
      float bb = b2[c];
      #pragma unroll
      for (int r=0;r<4;r++){
        h2h[(size_t)(m0 + quad*4 + r)*40 + c] = (_Float16)(acc[t][r] + bb);
      }
    }
  }
  if (col < 2){
    float cc = consts[16 + col];
    #pragma unroll
    for (int r=0;r<4;r++){
      int node = m0 + quad*4 + r;
      if (col == 0) a2i[node] = acc[3][r] + cc;
      else          a2j[node] = acc[3][r] + cc;
    }
  }
}

// ---------------- layer-2 fused softmax+aggregate + log_softmax ----------------
// FOUR nodes per wave; lanes ql<10 hold channel quads (uint2 of f16, hfma2).
__global__ __launch_bounds__(256) void k_agg2(const uint2* __restrict__ h2u2,
    const float* __restrict__ a2i, const float* __restrict__ a2j,
    const int* __restrict__ rowstart, const int* __restrict__ csr,
    const float* __restrict__ bias, float* __restrict__ out, int N){
  int lane = threadIdx.x & 63;
  int wid = (blockIdx.x*blockDim.x + threadIdx.x) >> 6;
  int qt = lane >> 4, ql = lane & 15;
  int n = wid*4 + qt;
  if (n >= N) return;
  bool act = ql < 10;
  unsigned cl = act ? (unsigned)ql : 0u;
  int rs = rowstart[n], re = rowstart[n+1];
  float ai = a2i[n];
  float wself = __expf(lrelu02(ai + a2j[n]));
  uint2 us = h2u2[(unsigned)n*10u + cl];
  __half2 whs = __float2half2_rn(wself);
  __half2 acc0 = __hmul2(whs, *(const __half2*)&us.x);
  __half2 acc1 = __hmul2(whs, *(const __half2*)&us.y);
  float den = wself;
  unsigned csA=0u, csB=0u; float ajA=0.f, ajB=0.f;
  if (rs < re){ csA = (unsigned)csr[rs]; ajA = a2j[csA]; }
  if (rs+1 < re){ csB = (unsigned)csr[rs+1]; ajB = a2j[csB]; }
  for (int e = rs; e < re; ++e){
    float w = __expf(lrelu02(ai + ajA));
    uint2 u = h2u2[csA*10u + cl];
    csA = csB; ajA = ajB;
    if (e+2 < re){ csB = (unsigned)csr[e+2]; ajB = a2j[csB]; }
    den += w;
    __half2 wh = __float2half2_rn(w);
    acc0 = __hfma2(wh, *(const __half2*)&u.x, acc0);
    acc1 = __hfma2(wh, *(const __half2*)&u.y, acc1);
  }
  float2 f0 = __half22float2(acc0), f1 = __half22float2(acc1);
  float invd = 1.f/(den + 1e-16f);
  const float4* b4 = (const float4*)(bias + 4*cl);
  float4 bb = b4[0];
  float v0 = f0.x*invd + bb.x, v1 = f0.y*invd + bb.y;
  float v2 = f1.x*invd + bb.z, v3 = f1.y*invd + bb.w;
  float mv = act ? fmaxf(fmaxf(v0,v1), fmaxf(v2,v3)) : -INFINITY;
  #pragma unroll
  for (int off = 1; off < 16; off <<= 1) mv = fmaxf(mv, __shfl_xor(mv, off));
  float se = act ? (__expf(v0-mv)+__expf(v1-mv)+__expf(v2-mv)+__expf(v3-mv)) : 0.f;
  #pragma unroll
  for (int off = 1; off < 16; off <<= 1) se += __shfl_xor(se, off);
  float ls = __logf(se);
  if (act){
    float4 o = make_float4(v0-mv-ls, v1-mv-ls, v2-mv-ls, v3-mv-ls);
    ((float4*)out)[(unsigned)n*10u + cl] = o;
  }
}

extern "C" void kernel_launch(void* const* d_in, const int* in_sizes, int n_in,
                              void* d_out, int out_size, void* d_ws, size_t ws_size,
                              hipStream_t stream){
  const float* x     = (const float*)d_in[0];
  const int*   ei    = (const int*)  d_in[1];
  const float* W1    = (const float*)d_in[2];
  const float* b1    = (const float*)d_in[3];
  const float* att1  = (const float*)d_in[4];
  const float* bias1 = (const float*)d_in[5];
  const float* W2    = (const float*)d_in[6];
  const float* b2    = (const float*)d_in[7];
  const float* att2  = (const float*)d_in[8];
  const float* bias2 = (const float*)d_in[9];
  int N = in_sizes[0] / 128;
  int E = in_sizes[1] / 2;
  const int* src = ei;
  const int* dst = ei + E;

  char* ws = (char*)d_ws;
  size_t off = 0;
  auto alloc = [&](size_t bytes)->char*{
    char* p = ws + off; off += (bytes + 255) & ~(size_t)255; return p;
  };
  _Float16* h1h = (_Float16*)alloc((size_t)N*128*2);
  _Float16* x2h = (_Float16*)alloc((size_t)N*128*2);
  _Float16* h2h = (_Float16*)alloc((size_t)N*40*2);
  float* a1i  = (float*)alloc((size_t)N*8*4);
  float* a1j  = (float*)alloc((size_t)N*8*4);
  float* a2i  = (float*)alloc((size_t)N*4);
  float* a2j  = (float*)alloc((size_t)N*4);
  _Float16* W1h   = (_Float16*)alloc(16384*2);
  _Float16* W2h   = (_Float16*)alloc(6144*2);
  _Float16* attB1 = (_Float16*)alloc(2048*2);
  _Float16* attB2 = (_Float16*)alloc(2048*2);
  float* consts = (float*)alloc(18*4);
  int*   deg  = (int*)  alloc((size_t)N*4);
  int*   rank = (int*)  alloc((size_t)E*4);
  int*   rowst= (int*)  alloc((size_t)(N+1)*4);
  int*   csr  = (int*)  alloc((size_t)E*4);
  int*   bsum = (int*)  alloc(4096);

  hipMemsetAsync(deg, 0, (size_t)N*4, stream);
  int nblk = (N + 1023)/1024;
  k_rank<<<(E+255)/256, 256, 0, stream>>>(dst, deg, rank, E);
  k_scanA<<<nblk, 256, 0, stream>>>(deg, rowst, bsum, N);
  k_scanB<<<1, 128, 0, stream>>>(bsum, nblk);
  k_scanC<<<(N+255)/256, 256, 0, stream>>>(rowst, bsum, N, E);
  k_fillx<<<1024, 256, 0, stream>>>(src, dst, rank, rowst, csr, E, N);
  k_prep<<<105, 256, 0, stream>>>(W1, b1, att1, W2, b2, att2, W1h, W2h, attB1, attB2, consts);

  int gblk = ((N+15)/16 + 3)/4;  // 4 waves/block, 16 nodes/wave
  k_gemm1<<<gblk, 256, 0, stream>>>(x, W1h, attB1, b1, consts, h1h, a1i, a1j, N);
  k_agg1<<<(N*64+255)/256, 256, 0, stream>>>((const uint4*)h1h, a1i, a1j, rowst, csr, bias1, (uint4*)x2h, N);

  k_gemm2<<<gblk, 256, 0, stream>>>(x2h, W2h, attB2, b2, consts, h2h, a2i, a2j, N);
  k_agg2<<<(N+15)/16, 256, 0, stream>>>((const uint2*)h2h, a2i, a2j, rowst, csr, bias2, (float*)d_out, N);
}